// Round 1
// baseline (433.606 us; speedup 1.0000x reference)
//
#include <hip/hip_runtime.h>
#include <hip/hip_bf16.h>

typedef short short8 __attribute__((ext_vector_type(8)));
typedef float f32x16 __attribute__((ext_vector_type(16)));

#define B_    16
#define C_    256
#define N_    4096
#define H_    4
#define D_    32
#define HID_  128
#define M3_   384
#define SCALE_ 0.17677669529663687f  /* 32^-0.5 */
#define EPS_  1e-5f

__device__ inline unsigned short f2bf(float f) {
  union { float f; unsigned u; } a; a.f = f;
  unsigned r = a.u + 0x7FFFu + ((a.u >> 16) & 1u);
  return (unsigned short)(r >> 16);
}
__device__ inline float bf2f(unsigned short s) {
  union { float f; unsigned u; } a; a.u = ((unsigned)s) << 16;
  return a.f;
}

// K1: qkv = W_qkv @ X per batch (bf16 MFMA), fused epilogue:
//  - q: softmax over d (32 rows within head) * SCALE -> qp[b][n][128] bf16
//  - k: exp(k) -> ek[b][128][n] bf16   (no max-sub; k ~ N(0,1))
//  - v: raw   -> vv[b][128][n] bf16    (1/4096 folded into context norm)
__global__ __launch_bounds__(256, 2) void k1_qkv(
    const float* __restrict__ x, const float* __restrict__ wqkv,
    unsigned short* __restrict__ qp, unsigned short* __restrict__ ek,
    unsigned short* __restrict__ vv)
{
  __shared__ __align__(16) unsigned short As[384 * 32];  // 24 KiB, W chunk (o, cc)
  __shared__ __align__(16) unsigned short Xs[64 * 32];   // 4 KiB, X chunk transposed (n, cc)
  __shared__ __align__(16) unsigned short Qt[64 * 128];  // 16 KiB, q' transpose buffer

  const int tid = threadIdx.x;
  const int b = blockIdx.y;
  const int n0 = blockIdx.x * 64;
  const int w = tid >> 6, lane = tid & 63;
  const int half = lane >> 5, lm = lane & 31;
  const int ntile = w & 1, mgrp = w >> 1;

  f32x16 acc[6];
  for (int i = 0; i < 6; ++i)
    for (int r = 0; r < 16; ++r) acc[i][r] = 0.0f;

  const float* xb = x + (size_t)b * C_ * N_ + n0;

  for (int kc = 0; kc < 8; ++kc) {
    const int c0 = kc * 32;
    __syncthreads();
    // stage W chunk: 384x32 fp32 -> bf16 (3072 float4, 12/thread)
    for (int it = 0; it < 12; ++it) {
      int idx = tid + it * 256;
      int o = idx >> 3, q4 = idx & 7;
      float4 wv = *(const float4*)(wqkv + (size_t)o * 256 + c0 + q4 * 4);
      unsigned short* dst = As + o * 32 + q4 * 4;
      dst[0] = f2bf(wv.x); dst[1] = f2bf(wv.y);
      dst[2] = f2bf(wv.z); dst[3] = f2bf(wv.w);
    }
    // stage X chunk transposed: rows cc (32) x cols (64) -> Xs[n][cc]
    for (int it = 0; it < 2; ++it) {
      int idx = tid + it * 256;
      int cc = idx >> 4, cq = idx & 15;
      float4 xv = *(const float4*)(xb + (size_t)(c0 + cc) * N_ + cq * 4);
      Xs[(cq * 4 + 0) * 32 + cc] = f2bf(xv.x);
      Xs[(cq * 4 + 1) * 32 + cc] = f2bf(xv.y);
      Xs[(cq * 4 + 2) * 32 + cc] = f2bf(xv.z);
      Xs[(cq * 4 + 3) * 32 + cc] = f2bf(xv.w);
    }
    __syncthreads();
    for (int ks = 0; ks < 2; ++ks) {
      short8 bfrag = *(const short8*)(Xs + (ntile * 32 + lm) * 32 + ks * 16 + half * 8);
      for (int i = 0; i < 6; ++i) {
        int mt = mgrp * 6 + i;
        short8 afrag = *(const short8*)(As + (mt * 32 + lm) * 32 + ks * 16 + half * 8);
        acc[i] = __builtin_amdgcn_mfma_f32_32x32x16_bf16(afrag, bfrag, acc[i], 0, 0, 0);
      }
    }
  }
  __syncthreads();

  const int colg = n0 + ntile * 32 + lm;
  for (int i = 0; i < 6; ++i) {
    int mt = mgrp * 6 + i;
    if (mt < 4) {
      // q softmax over the 32 rows (head dim) of this tile, per column
      float m = -1e30f;
      for (int r = 0; r < 16; ++r) m = fmaxf(m, acc[i][r]);
      m = fmaxf(m, __shfl_xor(m, 32));
      float e[16]; float s = 0.0f;
      for (int r = 0; r < 16; ++r) { e[r] = __expf(acc[i][r] - m); s += e[r]; }
      s += __shfl_xor(s, 32);
      float sc = SCALE_ / s;
      for (int r = 0; r < 16; ++r) {
        int row = (r & 3) + 8 * (r >> 2) + 4 * half;
        Qt[(ntile * 32 + lm) * 128 + mt * 32 + row] = f2bf(e[r] * sc);
      }
    } else if (mt < 8) {
      unsigned short* dst = ek + ((size_t)b * HID_ + (mt - 4) * 32) * N_;
      for (int r = 0; r < 16; ++r) {
        int row = (r & 3) + 8 * (r >> 2) + 4 * half;
        dst[(size_t)row * N_ + colg] = f2bf(__expf(acc[i][r]));
      }
    } else {
      unsigned short* dst = vv + ((size_t)b * HID_ + (mt - 8) * 32) * N_;
      for (int r = 0; r < 16; ++r) {
        int row = (r & 3) + 8 * (r >> 2) + 4 * half;
        dst[(size_t)row * N_ + colg] = f2bf(acc[i][r]);
      }
    }
  }
  __syncthreads();
  // coalesced copy Qt -> qp[b][n0..n0+63][128]
  {
    const int4* src = (const int4*)Qt;
    int4* dst = (int4*)(qp + ((size_t)b * N_ + n0) * 128);
    for (int it = 0; it < 4; ++it) dst[tid + it * 256] = src[tid + it * 256];
  }
}

// K2: partial context per (b, h, n-split): ctx[d][e] = sum_n ek[d,n]*v[e,n],
// plus per-d sum of ek. One wave per split; fragments loaded straight from global.
__global__ __launch_bounds__(256) void k2_ctx(
    const unsigned short* __restrict__ ek, const unsigned short* __restrict__ vv,
    float* __restrict__ pctx, float* __restrict__ psum)
{
  const int tid = threadIdx.x;
  const int w = tid >> 6, lane = tid & 63;
  const int half = lane >> 5, lm = lane & 31;
  const int h = blockIdx.y, b = blockIdx.z;
  const int ns = blockIdx.x * 4 + w;  // 0..7
  const size_t rowbase = ((size_t)b * HID_ + h * 32 + lm) * N_ + ns * 512 + half * 8;
  const unsigned short* ap = ek + rowbase;
  const unsigned short* bp = vv + rowbase;
  f32x16 acc;
  for (int r = 0; r < 16; ++r) acc[r] = 0.0f;
  float es = 0.0f;
  for (int ks = 0; ks < 32; ++ks) {
    short8 a = *(const short8*)(ap + ks * 16);
    short8 bb = *(const short8*)(bp + ks * 16);
    for (int j = 0; j < 8; ++j) es += bf2f((unsigned short)a[j]);
    acc = __builtin_amdgcn_mfma_f32_32x32x16_bf16(a, bb, acc, 0, 0, 0);
  }
  es += __shfl_xor(es, 32);
  float* pc = pctx + (((size_t)(b * H_ + h) * 8 + ns) << 10);
  for (int r = 0; r < 16; ++r) {
    int row = (r & 3) + 8 * (r >> 2) + 4 * half;
    pc[row * 32 + lm] = acc[r];
  }
  if (half == 0) psum[((size_t)(b * H_ + h) * 8 + ns) * 32 + lm] = es;
}

// K2b: reduce partials, normalize context (softmax denom and 1/4096),
// pre-contract with w_out:  W_eff[oc][h*32+d] = sum_e w_out[oc][h*32+e]*ctx'[h][d][e]
__global__ __launch_bounds__(256) void k2b_weff(
    const float* __restrict__ pctx, const float* __restrict__ psum,
    const float* __restrict__ wout, unsigned short* __restrict__ weff)
{
  __shared__ float ctxs[H_][32][32];  // 16 KiB
  __shared__ float inv[H_][32];
  const int tid = threadIdx.x;
  const int b = blockIdx.x;
  if (tid < 128) {
    int h = tid >> 5, d = tid & 31;
    float s = 0.0f;
    for (int ns = 0; ns < 8; ++ns) s += psum[((size_t)(b * H_ + h) * 8 + ns) * 32 + d];
    inv[h][d] = 1.0f / (s * 4096.0f);
  }
  __syncthreads();
  for (int it = 0; it < 16; ++it) {
    int idx = tid + it * 256;            // h*1024 + d*32 + e
    int h = idx >> 10, de = idx & 1023, d = de >> 5;
    float s = 0.0f;
    const float* pc = pctx + ((size_t)(b * H_ + h) * 8) * 1024 + de;
    for (int ns = 0; ns < 8; ++ns) s += pc[ns * 1024];
    ctxs[h][d][de & 31] = s * inv[h][d];
  }
  __syncthreads();
  const int oc = tid;
  const float* wrow = wout + (size_t)oc * HID_;
  unsigned short* dst = weff + ((size_t)b * 256 + oc) * HID_;
  for (int h = 0; h < H_; ++h) {
    float wr[32];
    for (int e = 0; e < 32; ++e) wr[e] = wrow[h * 32 + e];
    for (int d = 0; d < 32; ++d) {
      float s = 0.0f;
      for (int e = 0; e < 32; ++e) s += wr[e] * ctxs[h][d][e];
      dst[h * 32 + d] = f2bf(s);
    }
  }
}

// K3: out = W_eff_b @ q'^T + b_out, channel LayerNorm per column, * g, store fp32.
__global__ __launch_bounds__(256, 2) void k3_out(
    const unsigned short* __restrict__ weff, const unsigned short* __restrict__ qp,
    const float* __restrict__ bout, const float* __restrict__ g,
    float* __restrict__ out)
{
  __shared__ __align__(16) unsigned short Ws[256 * 64];  // 32 KiB, W_eff K-chunk
  __shared__ __align__(16) unsigned short Qs[64 * 128];  // 16 KiB, q' tile (n, dh)
  __shared__ float part_s[2][64], part_s2[2][64];
  __shared__ float st_mu[64], st_rs[64];

  const int tid = threadIdx.x;
  const int b = blockIdx.y;
  const int n0 = blockIdx.x * 64;
  const int w = tid >> 6, lane = tid & 63;
  const int half = lane >> 5, lm = lane & 31;
  const int ntile = w & 1, mgrp = w >> 1;

  // stage q' tile once
  {
    const int4* s2 = (const int4*)(qp + ((size_t)b * N_ + n0) * 128);
    int4* d2 = (int4*)Qs;
    for (int it = 0; it < 4; ++it) d2[tid + it * 256] = s2[tid + it * 256];
  }

  f32x16 acc[4];
  for (int i = 0; i < 4; ++i)
    for (int r = 0; r < 16; ++r) acc[i][r] = 0.0f;

  for (int c = 0; c < 2; ++c) {
    __syncthreads();
    // stage W_eff chunk: 256 rows x 64 bf16 (2048 int4, 8/thread)
    const unsigned short* wsrc = weff + (size_t)b * 256 * 128 + c * 64;
    for (int it = 0; it < 8; ++it) {
      int idx = tid + it * 256;
      int oc = idx >> 3, grp = idx & 7;
      *(int4*)(Ws + oc * 64 + grp * 8) = *(const int4*)(wsrc + (size_t)oc * 128 + grp * 8);
    }
    __syncthreads();
    for (int ks = 0; ks < 4; ++ks) {
      short8 bfrag = *(const short8*)(Qs + (ntile * 32 + lm) * 128 + c * 64 + ks * 16 + half * 8);
      for (int i = 0; i < 4; ++i) {
        int mt = mgrp * 4 + i;
        short8 afrag = *(const short8*)(Ws + (mt * 32 + lm) * 64 + ks * 16 + half * 8);
        acc[i] = __builtin_amdgcn_mfma_f32_32x32x16_bf16(afrag, bfrag, acc[i], 0, 0, 0);
      }
    }
  }

  // add bias in place; per-column stats (col = ntile*32+lm)
  float s = 0.0f, s2 = 0.0f;
  for (int i = 0; i < 4; ++i) {
    int mt = mgrp * 4 + i;
    for (int r = 0; r < 16; ++r) {
      int row = mt * 32 + (r & 3) + 8 * (r >> 2) + 4 * half;
      acc[i][r] += bout[row];
      float v = acc[i][r];
      s += v; s2 += v * v;
    }
  }
  s += __shfl_xor(s, 32);
  s2 += __shfl_xor(s2, 32);
  if (half == 0) { part_s[mgrp][ntile * 32 + lm] = s; part_s2[mgrp][ntile * 32 + lm] = s2; }
  __syncthreads();
  if (tid < 64) {
    float S = part_s[0][tid] + part_s[1][tid];
    float S2 = part_s2[0][tid] + part_s2[1][tid];
    float mu = S * (1.0f / 256.0f);
    float var = S2 * (1.0f / 256.0f) - mu * mu;
    st_mu[tid] = mu;
    st_rs[tid] = rsqrtf(var + EPS_);
  }
  __syncthreads();

  const int col = ntile * 32 + lm;
  const float mu = st_mu[col];
  const float rs = st_rs[col];
  float* ob = out + (size_t)b * C_ * N_ + n0 + col;
  for (int i = 0; i < 4; ++i) {
    int mt = mgrp * 4 + i;
    for (int r = 0; r < 16; ++r) {
      int row = mt * 32 + (r & 3) + 8 * (r >> 2) + 4 * half;
      ob[(size_t)row * N_] = (acc[i][r] - mu) * rs * g[row];
    }
  }
}

extern "C" void kernel_launch(void* const* d_in, const int* in_sizes, int n_in,
                              void* d_out, int out_size, void* d_ws, size_t ws_size,
                              hipStream_t stream) {
  (void)in_sizes; (void)n_in; (void)out_size; (void)ws_size;
  const float* x    = (const float*)d_in[0];
  const float* wqkv = (const float*)d_in[1];
  const float* wout = (const float*)d_in[2];
  const float* bout = (const float*)d_in[3];
  const float* g    = (const float*)d_in[4];
  float* out = (float*)d_out;

  char* ws = (char*)d_ws;
  unsigned short* qp   = (unsigned short*)(ws);                 // 16 MiB  (b, n, 128) bf16
  unsigned short* ek   = (unsigned short*)(ws + (16u << 20));   // 16 MiB  (b, 128, n) bf16
  unsigned short* vv   = (unsigned short*)(ws + (32u << 20));   // 16 MiB  (b, 128, n) bf16
  float*          pctx = (float*)(ws + (48u << 20));            // 2 MiB   (b,h,8,32,32) fp32
  float*          psum = (float*)(ws + (50u << 20));            // 64 KiB  (b,h,8,32) fp32
  unsigned short* weff = (unsigned short*)(ws + (51u << 20));   // 1 MiB   (b,256,128) bf16

  k1_qkv<<<dim3(64, 16), 256, 0, stream>>>(x, wqkv, qp, ek, vv);
  k2_ctx<<<dim3(2, 4, 16), 256, 0, stream>>>(ek, vv, pctx, psum);
  k2b_weff<<<16, 256, 0, stream>>>(pctx, psum, wout, weff);
  k3_out<<<dim3(64, 16), 256, 0, stream>>>(weff, qp, bout, g, out);
}

// Round 2
// 336.306 us; speedup vs baseline: 1.2893x; 1.2893x over previous
//
#include <hip/hip_runtime.h>

typedef short short8 __attribute__((ext_vector_type(8)));
typedef float f32x16 __attribute__((ext_vector_type(16)));
typedef unsigned short ushort_t;

#define B_    16
#define C_    256
#define N_    4096
#define H_    4
#define HID_  128
#define SCALE_ 0.17677669529663687f  /* 32^-0.5 */
#define EPS_  1e-5f

__device__ inline ushort_t f2bf(float f) {
  union { float f; unsigned u; } a; a.f = f;
  unsigned r = a.u + 0x7FFFu + ((a.u >> 16) & 1u);
  return (ushort_t)(r >> 16);
}

__device__ inline short8 ld_frag16(const ushort_t* p) {  // 16B-aligned
  return __builtin_bit_cast(short8, *(const int4*)p);
}
__device__ inline short8 ld_frag8(const ushort_t* p) {   // 8B-aligned (2x b64)
  int2 a = *(const int2*)p, b = *(const int2*)(p + 4);
  int4 t; t.x = a.x; t.y = a.y; t.z = b.x; t.w = b.y;
  return __builtin_bit_cast(short8, t);
}
__device__ inline short8 ld_frag4(const ushort_t* p) {   // 4B-aligned (4x b32)
  int4 t;
  t.x = *(const int*)(p);     t.y = *(const int*)(p + 2);
  t.z = *(const int*)(p + 4); t.w = *(const int*)(p + 6);
  return __builtin_bit_cast(short8, t);
}

// K0: pre-convert w_qkv (384x256 fp32) to bf16 once.
__global__ void k0_wconv(const float* __restrict__ w, ushort_t* __restrict__ wb) {
  int idx = blockIdx.x * 256 + threadIdx.x;      // 24576 float4s
  float4 v = ((const float4*)w)[idx];
  int2 o;
  o.x = (int)f2bf(v.x) | ((int)f2bf(v.y) << 16);
  o.y = (int)f2bf(v.z) | ((int)f2bf(v.w) << 16);
  *(int2*)(wb + (size_t)idx * 4) = o;
}

// K1: qkv GEMM (bf16 MFMA) + fused epilogue:
//  q: softmax over d * SCALE -> qp[b][n][128] (coalesced int4 via padded LDS)
//  k,v: exp(k), v kept in LDS (d-major, padded); per-block partial context
//       pctx[b][h][blk][32][32] = sum_{n in blk} exp(k)[d,n]*v[e,n]  (MFMA)
//       psum[b][h][blk][32]     = sum_{n in blk} exp(k)[d,n]         (MFMA vs ones)
__global__ __launch_bounds__(256, 2) void k1_qkv(
    const float* __restrict__ x, const ushort_t* __restrict__ wb,
    ushort_t* __restrict__ qp, float* __restrict__ pctx, float* __restrict__ psum)
{
  __shared__ __align__(16) union {
    struct { ushort_t As[384 * 40]; ushort_t Xs[64 * 34]; } s1;   // 35 KiB
    struct { ushort_t Qt[64 * 132]; ushort_t kt[128 * 68]; ushort_t vt[128 * 68]; } s2; // 50.5 KiB
  } sm;

  const int tid = threadIdx.x;
  const int b = blockIdx.y;
  const int blk = blockIdx.x;
  const int n0 = blk * 64;
  const int w = tid >> 6, lane = tid & 63;
  const int half = lane >> 5, lm = lane & 31;
  const int ntile = w & 1, mgrp = w >> 1;

  f32x16 acc[6];
  for (int i = 0; i < 6; ++i)
    for (int r = 0; r < 16; ++r) acc[i][r] = 0.0f;

  const float* xb = x + (size_t)b * C_ * N_ + n0;

  for (int kc = 0; kc < 8; ++kc) {
    const int c0 = kc * 32;
    __syncthreads();
    // stage W chunk: 384 rows x 32 bf16 (int4 copies, padded rows of 40 shorts)
    for (int it = 0; it < 6; ++it) {
      int idx = tid + it * 256;
      int o = idx >> 2, q4 = idx & 3;
      *(int4*)(sm.s1.As + o * 40 + q4 * 8) = *(const int4*)(wb + (size_t)o * 256 + c0 + q4 * 8);
    }
    // stage X chunk transposed: Xs[n][cc], padded rows of 34 shorts
    for (int it = 0; it < 8; ++it) {
      int idx = tid + it * 256;
      int cc = idx >> 6, nn = idx & 63;
      sm.s1.Xs[nn * 34 + cc] = f2bf(xb[(size_t)(c0 + cc) * N_ + nn]);
    }
    __syncthreads();
    for (int ks = 0; ks < 2; ++ks) {
      short8 bfrag = ld_frag4(sm.s1.Xs + (ntile * 32 + lm) * 34 + ks * 16 + half * 8);
      for (int i = 0; i < 6; ++i) {
        int mt = mgrp * 6 + i;
        short8 afrag = ld_frag16(sm.s1.As + (mt * 32 + lm) * 40 + ks * 16 + half * 8);
        acc[i] = __builtin_amdgcn_mfma_f32_32x32x16_bf16(afrag, bfrag, acc[i], 0, 0, 0);
      }
    }
  }
  __syncthreads();  // s1 dead; s2 live from here

  for (int i = 0; i < 6; ++i) {
    int mt = mgrp * 6 + i;
    if (mt < 4) {
      // q softmax over 32 rows (head dim) per column
      float m = -1e30f;
      for (int r = 0; r < 16; ++r) m = fmaxf(m, acc[i][r]);
      m = fmaxf(m, __shfl_xor(m, 32));
      float e[16]; float s = 0.0f;
      for (int r = 0; r < 16; ++r) { e[r] = __expf(acc[i][r] - m); s += e[r]; }
      s += __shfl_xor(s, 32);
      float sc = SCALE_ / s;
      for (int r = 0; r < 16; ++r) {
        int row = (r & 3) + 8 * (r >> 2) + 4 * half;
        sm.s2.Qt[(ntile * 32 + lm) * 132 + mt * 32 + row] = f2bf(e[r] * sc);
      }
    } else if (mt < 8) {
      int kr = (mt - 4) * 32;
      for (int r = 0; r < 16; ++r) {
        int row = (r & 3) + 8 * (r >> 2) + 4 * half;
        sm.s2.kt[(kr + row) * 68 + ntile * 32 + lm] = f2bf(__expf(acc[i][r]));
      }
    } else {
      int vr = (mt - 8) * 32;
      for (int r = 0; r < 16; ++r) {
        int row = (r & 3) + 8 * (r >> 2) + 4 * half;
        sm.s2.vt[(vr + row) * 68 + ntile * 32 + lm] = f2bf(acc[i][r]);
      }
    }
  }
  __syncthreads();

  // per-head partial context via MFMA; wave w handles head w
  {
    const int h = w;
    f32x16 cacc, eacc;
    for (int r = 0; r < 16; ++r) { cacc[r] = 0.0f; eacc[r] = 0.0f; }
    short8 ones;
    for (int j = 0; j < 8; ++j) ones[j] = (short)0x3F80;  // bf16 1.0
    for (int nb = 0; nb < 4; ++nb) {
      short8 af = ld_frag8(sm.s2.kt + (h * 32 + lm) * 68 + nb * 16 + half * 8);
      short8 bf = ld_frag8(sm.s2.vt + (h * 32 + lm) * 68 + nb * 16 + half * 8);
      cacc = __builtin_amdgcn_mfma_f32_32x32x16_bf16(af, bf, cacc, 0, 0, 0);
      eacc = __builtin_amdgcn_mfma_f32_32x32x16_bf16(af, ones, eacc, 0, 0, 0);
    }
    float* pc = pctx + ((size_t)(b * H_ + h) * 64 + blk) * 1024;
    for (int r = 0; r < 16; ++r) {
      int row = (r & 3) + 8 * (r >> 2) + 4 * half;
      pc[row * 32 + lm] = cacc[r];
    }
    if (lm == 0) {
      float* ps = psum + ((size_t)(b * H_ + h) * 64 + blk) * 32;
      for (int r = 0; r < 16; ++r) {
        int row = (r & 3) + 8 * (r >> 2) + 4 * half;
        ps[row] = eacc[r];
      }
    }
  }
  __syncthreads();

  // coalesced copy Qt -> qp[b][n0..n0+63][128] (b64 reads from padded LDS)
  {
    int4* dst = (int4*)(qp + ((size_t)b * N_ + n0) * 128);
    for (int it = 0; it < 4; ++it) {
      int idx = tid + it * 256;              // 0..1023
      int row = idx >> 4, c8 = idx & 15;
      const ushort_t* src = sm.s2.Qt + row * 132 + c8 * 8;
      int2 u0 = *(const int2*)src, u1 = *(const int2*)(src + 4);
      int4 o; o.x = u0.x; o.y = u0.y; o.z = u1.x; o.w = u1.y;
      dst[idx] = o;
    }
  }
}

// K2b: reduce 64 partials per (b,h), normalize (softmax denom & 1/4096),
// pre-contract with w_out: weff[b][oc][h*32+d] = sum_e wout[oc][h*32+e]*ctx'[d][e]
__global__ __launch_bounds__(256) void k2b_weff(
    const float* __restrict__ pctx, const float* __restrict__ psum,
    const float* __restrict__ wout, ushort_t* __restrict__ weff)
{
  __shared__ float ctxs[32][32];
  __shared__ float inv[32];
  const int tid = threadIdx.x;
  const int h = blockIdx.x, b = blockIdx.y;
  if (tid < 32) {
    float s = 0.0f;
    const float* ps = psum + (size_t)(b * H_ + h) * 64 * 32 + tid;
    for (int blkk = 0; blkk < 64; ++blkk) s += ps[blkk * 32];
    inv[tid] = 1.0f / (s * 4096.0f);
  }
  __syncthreads();
  for (int it = 0; it < 4; ++it) {
    int de = tid + it * 256;
    float s = 0.0f;
    const float* pc = pctx + (size_t)(b * H_ + h) * 64 * 1024 + de;
    for (int blkk = 0; blkk < 64; ++blkk) s += pc[blkk * 1024];
    ctxs[de >> 5][de & 31] = s * inv[de >> 5];
  }
  __syncthreads();
  const float* wrow = wout + (size_t)tid * HID_ + h * 32;
  float wr[32];
  for (int e = 0; e < 32; ++e) wr[e] = wrow[e];
  union { ushort_t u[32]; int4 v4[4]; } tmp;
  for (int d = 0; d < 32; ++d) {
    float s = 0.0f;
    for (int e = 0; e < 32; ++e) s += wr[e] * ctxs[d][e];
    tmp.u[d] = f2bf(s);
  }
  int4* dp = (int4*)(weff + ((size_t)b * 256 + tid) * HID_ + h * 32);
  for (int j = 0; j < 4; ++j) dp[j] = tmp.v4[j];
}

// K3: out = W_eff_b @ q'^T + b_out, channel LayerNorm per column, * g, fp32 store.
__global__ __launch_bounds__(256, 2) void k3_out(
    const ushort_t* __restrict__ weff, const ushort_t* __restrict__ qp,
    const float* __restrict__ bout, const float* __restrict__ g,
    float* __restrict__ out)
{
  __shared__ __align__(16) ushort_t Ws[256 * 72];   // 36 KiB (padded rows)
  __shared__ __align__(16) ushort_t Qs[64 * 136];   // 17 KiB (padded rows)
  __shared__ float part_s[2][64], part_s2[2][64];
  __shared__ float st_mu[64], st_rs[64];

  const int tid = threadIdx.x;
  const int b = blockIdx.y;
  const int n0 = blockIdx.x * 64;
  const int w = tid >> 6, lane = tid & 63;
  const int half = lane >> 5, lm = lane & 31;
  const int ntile = w & 1, mgrp = w >> 1;

  // stage q' tile (padded)
  {
    const int4* s2 = (const int4*)(qp + ((size_t)b * N_ + n0) * 128);
    for (int it = 0; it < 4; ++it) {
      int idx = tid + it * 256;
      int row = idx >> 4, c8 = idx & 15;
      *(int4*)(Qs + row * 136 + c8 * 8) = s2[idx];
    }
  }

  f32x16 acc[4];
  for (int i = 0; i < 4; ++i)
    for (int r = 0; r < 16; ++r) acc[i][r] = 0.0f;

  for (int c = 0; c < 2; ++c) {
    __syncthreads();
    const ushort_t* wsrc = weff + (size_t)b * 256 * 128 + c * 64;
    for (int it = 0; it < 8; ++it) {
      int idx = tid + it * 256;
      int oc = idx >> 3, grp = idx & 7;
      *(int4*)(Ws + oc * 72 + grp * 8) = *(const int4*)(wsrc + (size_t)oc * 128 + grp * 8);
    }
    __syncthreads();
    for (int ks = 0; ks < 4; ++ks) {
      short8 bfrag = ld_frag16(Qs + (ntile * 32 + lm) * 136 + c * 64 + ks * 16 + half * 8);
      for (int i = 0; i < 4; ++i) {
        int mt = mgrp * 4 + i;
        short8 afrag = ld_frag16(Ws + (mt * 32 + lm) * 72 + ks * 16 + half * 8);
        acc[i] = __builtin_amdgcn_mfma_f32_32x32x16_bf16(afrag, bfrag, acc[i], 0, 0, 0);
      }
    }
  }

  float s = 0.0f, s2 = 0.0f;
  for (int i = 0; i < 4; ++i) {
    int mt = mgrp * 4 + i;
    for (int r = 0; r < 16; ++r) {
      int row = mt * 32 + (r & 3) + 8 * (r >> 2) + 4 * half;
      acc[i][r] += bout[row];
      float v = acc[i][r];
      s += v; s2 += v * v;
    }
  }
  s += __shfl_xor(s, 32);
  s2 += __shfl_xor(s2, 32);
  if (half == 0) { part_s[mgrp][ntile * 32 + lm] = s; part_s2[mgrp][ntile * 32 + lm] = s2; }
  __syncthreads();
  if (tid < 64) {
    float S = part_s[0][tid] + part_s[1][tid];
    float S2 = part_s2[0][tid] + part_s2[1][tid];
    float mu = S * (1.0f / 256.0f);
    float var = S2 * (1.0f / 256.0f) - mu * mu;
    st_mu[tid] = mu;
    st_rs[tid] = rsqrtf(var + EPS_);
  }
  __syncthreads();

  const int col = ntile * 32 + lm;
  const float mu = st_mu[col];
  const float rs = st_rs[col];
  float* ob = out + (size_t)b * C_ * N_ + n0 + col;
  for (int i = 0; i < 4; ++i) {
    int mt = mgrp * 4 + i;
    for (int r = 0; r < 16; ++r) {
      int row = mt * 32 + (r & 3) + 8 * (r >> 2) + 4 * half;
      ob[(size_t)row * N_] = (acc[i][r] - mu) * rs * g[row];
    }
  }
}

extern "C" void kernel_launch(void* const* d_in, const int* in_sizes, int n_in,
                              void* d_out, int out_size, void* d_ws, size_t ws_size,
                              hipStream_t stream) {
  (void)in_sizes; (void)n_in; (void)out_size; (void)ws_size;
  const float* x    = (const float*)d_in[0];
  const float* wqkv = (const float*)d_in[1];
  const float* wout = (const float*)d_in[2];
  const float* bout = (const float*)d_in[3];
  const float* g    = (const float*)d_in[4];
  float* out = (float*)d_out;

  char* ws = (char*)d_ws;
  ushort_t* qp   = (ushort_t*)(ws);                      // 16 MiB (b, n, 128) bf16
  float*    pctx = (float*)(ws + ((size_t)16 << 20));    // 16 MiB (b,h,64,32,32) fp32
  float*    psum = (float*)(ws + ((size_t)32 << 20));    // 512 KiB (b,h,64,32) fp32
  ushort_t* weff = (ushort_t*)(ws + ((size_t)33 << 20)); // 1 MiB (b,256,128) bf16
  ushort_t* wb   = (ushort_t*)(ws + ((size_t)34 << 20)); // 192 KiB (384,256) bf16

  k0_wconv<<<96, 256, 0, stream>>>(wqkv, wb);
  k1_qkv<<<dim3(64, 16), 256, 0, stream>>>(x, wb, qp, pctx, psum);
  k2b_weff<<<dim3(4, 16), 256, 0, stream>>>(pctx, psum, wout, weff);
  k3_out<<<dim3(64, 16), 256, 0, stream>>>(weff, qp, bout, g, out);
}

// Round 3
// 260.904 us; speedup vs baseline: 1.6619x; 1.2890x over previous
//
#include <hip/hip_runtime.h>

typedef short short8 __attribute__((ext_vector_type(8)));
typedef float f32x16 __attribute__((ext_vector_type(16)));
typedef unsigned short ushort_t;

#define B_    16
#define C_    256
#define N_    4096
#define H_    4
#define HID_  128
#define SCALE_ 0.17677669529663687f  /* 32^-0.5 */
#define EPS_  1e-5f

__device__ inline ushort_t f2bf(float f) {
  union { float f; unsigned u; } a; a.f = f;
  unsigned r = a.u + 0x7FFFu + ((a.u >> 16) & 1u);
  return (ushort_t)(r >> 16);
}

__device__ inline short8 ld_frag16(const ushort_t* p) {  // 16B-aligned
  return __builtin_bit_cast(short8, *(const int4*)p);
}
__device__ inline short8 ld_frag8(const ushort_t* p) {   // 8B-aligned (2x b64)
  int2 a = *(const int2*)p, b = *(const int2*)(p + 4);
  int4 t; t.x = a.x; t.y = a.y; t.z = b.x; t.w = b.y;
  return __builtin_bit_cast(short8, t);
}
__device__ inline short8 ld_frag4(const ushort_t* p) {   // 4B-aligned (4x b32)
  int4 t;
  t.x = *(const int*)(p);     t.y = *(const int*)(p + 2);
  t.z = *(const int*)(p + 4); t.w = *(const int*)(p + 6);
  return __builtin_bit_cast(short8, t);
}

// K0: pre-convert w_qkv (384x256 fp32) to bf16 once.
__global__ void k0_wconv(const float* __restrict__ w, ushort_t* __restrict__ wb) {
  int idx = blockIdx.x * 256 + threadIdx.x;      // 24576 float4s
  float4 v = ((const float4*)w)[idx];
  int2 o;
  o.x = (int)f2bf(v.x) | ((int)f2bf(v.y) << 16);
  o.y = (int)f2bf(v.z) | ((int)f2bf(v.w) << 16);
  *(int2*)(wb + (size_t)idx * 4) = o;
}

// K1: qkv GEMM. X tile staged to LDS ONCE (transposed, padded pitch 258);
// W fragments loaded directly from global (bf16, c-contiguous, L2-resident).
// Barrier-free K-loop of 96 MFMAs, then fused epilogue:
//  q: softmax over d * SCALE -> qp[b][n][128]
//  k,v: exp(k), v -> LDS (d-major), per-block partial context via MFMA:
//       pctx[b][h][blk][32][32], psum[b][h][blk][32]
__global__ __launch_bounds__(256, 3) void k1_qkv(
    const float* __restrict__ x, const ushort_t* __restrict__ wb,
    ushort_t* __restrict__ qp, float* __restrict__ pctx, float* __restrict__ psum)
{
  __shared__ __align__(16) union {
    struct { ushort_t Xs[64 * 258]; } s1;                                // 33 KiB
    struct { ushort_t Qt[64 * 132]; ushort_t kt[128 * 68]; ushort_t vt[128 * 68]; } s2; // 50.5 KiB
  } sm;

  const int tid = threadIdx.x;
  const int b = blockIdx.y;
  const int blk = blockIdx.x;
  const int n0 = blk * 64;
  const int w = tid >> 6, lane = tid & 63;
  const int half = lane >> 5, lm = lane & 31;
  const int ntile = w & 1, mgrp = w >> 1;

  f32x16 acc[6];
  for (int i = 0; i < 6; ++i)
    for (int r = 0; r < 16; ++r) acc[i][r] = 0.0f;

  // stage whole X tile transposed: Xs[nn][cc], pitch 258 shorts (129 dw, odd)
  {
    const float* xb = x + (size_t)b * C_ * N_ + n0;
    for (int it = 0; it < 16; ++it) {
      int idx = it * 256 + tid;        // 0..4095
      int cc = idx >> 4;               // channel 0..255
      int n4 = idx & 15;               // group of 4 n
      float4 v = *(const float4*)(xb + (size_t)cc * N_ + n4 * 4);
      ushort_t* dst = sm.s1.Xs + cc;
      dst[(n4 * 4 + 0) * 258] = f2bf(v.x);
      dst[(n4 * 4 + 1) * 258] = f2bf(v.y);
      dst[(n4 * 4 + 2) * 258] = f2bf(v.z);
      dst[(n4 * 4 + 3) * 258] = f2bf(v.w);
    }
  }
  __syncthreads();

  // barrier-free K-loop: B-frag from LDS, A-frag direct from global (L2)
  {
    const int nrow = ntile * 32 + lm;
    const ushort_t* wbase = wb + (size_t)(mgrp * 6 * 32 + lm) * 256 + half * 8;
    for (int kc = 0; kc < 16; ++kc) {
      short8 bfrag = ld_frag4(sm.s1.Xs + nrow * 258 + kc * 16 + half * 8);
      for (int i = 0; i < 6; ++i) {
        short8 af = ld_frag16(wbase + (size_t)i * 32 * 256 + kc * 16);
        acc[i] = __builtin_amdgcn_mfma_f32_32x32x16_bf16(af, bfrag, acc[i], 0, 0, 0);
      }
    }
  }
  __syncthreads();  // s1 dead; s2 live from here

  for (int i = 0; i < 6; ++i) {
    int mt = mgrp * 6 + i;
    if (mt < 4) {
      // q softmax over 32 rows (head dim) per column
      float m = -1e30f;
      for (int r = 0; r < 16; ++r) m = fmaxf(m, acc[i][r]);
      m = fmaxf(m, __shfl_xor(m, 32));
      float e[16]; float s = 0.0f;
      for (int r = 0; r < 16; ++r) { e[r] = __expf(acc[i][r] - m); s += e[r]; }
      s += __shfl_xor(s, 32);
      float sc = SCALE_ / s;
      for (int r = 0; r < 16; ++r) {
        int row = (r & 3) + 8 * (r >> 2) + 4 * half;
        sm.s2.Qt[(ntile * 32 + lm) * 132 + mt * 32 + row] = f2bf(e[r] * sc);
      }
    } else if (mt < 8) {
      int kr = (mt - 4) * 32;
      for (int r = 0; r < 16; ++r) {
        int row = (r & 3) + 8 * (r >> 2) + 4 * half;
        sm.s2.kt[(kr + row) * 68 + ntile * 32 + lm] = f2bf(__expf(acc[i][r]));
      }
    } else {
      int vr = (mt - 8) * 32;
      for (int r = 0; r < 16; ++r) {
        int row = (r & 3) + 8 * (r >> 2) + 4 * half;
        sm.s2.vt[(vr + row) * 68 + ntile * 32 + lm] = f2bf(acc[i][r]);
      }
    }
  }
  __syncthreads();

  // per-head partial context via MFMA; wave w handles head w
  {
    const int h = w;
    f32x16 cacc, eacc;
    for (int r = 0; r < 16; ++r) { cacc[r] = 0.0f; eacc[r] = 0.0f; }
    short8 ones;
    for (int j = 0; j < 8; ++j) ones[j] = (short)0x3F80;  // bf16 1.0
    for (int nb = 0; nb < 4; ++nb) {
      short8 af = ld_frag8(sm.s2.kt + (h * 32 + lm) * 68 + nb * 16 + half * 8);
      short8 bf = ld_frag8(sm.s2.vt + (h * 32 + lm) * 68 + nb * 16 + half * 8);
      cacc = __builtin_amdgcn_mfma_f32_32x32x16_bf16(af, bf, cacc, 0, 0, 0);
      eacc = __builtin_amdgcn_mfma_f32_32x32x16_bf16(af, ones, eacc, 0, 0, 0);
    }
    float* pc = pctx + ((size_t)(b * H_ + h) * 64 + blk) * 1024;
    for (int r = 0; r < 16; ++r) {
      int row = (r & 3) + 8 * (r >> 2) + 4 * half;
      pc[row * 32 + lm] = cacc[r];
    }
    if (lm == 0) {
      float* ps = psum + ((size_t)(b * H_ + h) * 64 + blk) * 32;
      for (int r = 0; r < 16; ++r) {
        int row = (r & 3) + 8 * (r >> 2) + 4 * half;
        ps[row] = eacc[r];
      }
    }
  }
  __syncthreads();

  // coalesced copy Qt -> qp[b][n0..n0+63][128]
  {
    int4* dst = (int4*)(qp + ((size_t)b * N_ + n0) * 128);
    for (int it = 0; it < 4; ++it) {
      int idx = tid + it * 256;              // 0..1023
      int row = idx >> 4, c8 = idx & 15;
      const ushort_t* src = sm.s2.Qt + row * 132 + c8 * 8;
      int2 u0 = *(const int2*)src, u1 = *(const int2*)(src + 4);
      int4 o; o.x = u0.x; o.y = u0.y; o.z = u1.x; o.w = u1.y;
      dst[idx] = o;
    }
  }
}

// K2b: reduce 64 partials per (b,h), normalize (softmax denom & 1/4096),
// pre-contract with w_out: weff[b][oc][h*32+d] = sum_e wout[oc][h*32+e]*ctx'[d][e]
__global__ __launch_bounds__(256) void k2b_weff(
    const float* __restrict__ pctx, const float* __restrict__ psum,
    const float* __restrict__ wout, ushort_t* __restrict__ weff)
{
  __shared__ float ctxs[32][32];
  __shared__ float inv[32];
  const int tid = threadIdx.x;
  const int h = blockIdx.x, b = blockIdx.y;
  if (tid < 32) {
    float s = 0.0f;
    const float* ps = psum + (size_t)(b * H_ + h) * 64 * 32 + tid;
    for (int blkk = 0; blkk < 64; ++blkk) s += ps[blkk * 32];
    inv[tid] = 1.0f / (s * 4096.0f);
  }
  __syncthreads();
  for (int it = 0; it < 4; ++it) {
    int de = tid + it * 256;
    float s = 0.0f;
    const float* pc = pctx + (size_t)(b * H_ + h) * 64 * 1024 + de;
    for (int blkk = 0; blkk < 64; ++blkk) s += pc[blkk * 1024];
    ctxs[de >> 5][de & 31] = s * inv[de >> 5];
  }
  __syncthreads();
  const float* wrow = wout + (size_t)tid * HID_ + h * 32;
  float wr[32];
  for (int e = 0; e < 32; ++e) wr[e] = wrow[e];
  union { ushort_t u[32]; int4 v4[4]; } tmp;
  for (int d = 0; d < 32; ++d) {
    float s = 0.0f;
    for (int e = 0; e < 32; ++e) s += wr[e] * ctxs[d][e];
    tmp.u[d] = f2bf(s);
  }
  int4* dp = (int4*)(weff + ((size_t)b * 256 + tid) * HID_ + h * 32);
  for (int j = 0; j < 4; ++j) dp[j] = tmp.v4[j];
}

// K3: out = W_eff_b @ q'^T + b_out, channel LayerNorm per column, * g, fp32 store.
// W_eff fragments direct from global (64 KiB/batch, L2-resident); only q' in LDS.
__global__ __launch_bounds__(256, 4) void k3_out(
    const ushort_t* __restrict__ weff, const ushort_t* __restrict__ qp,
    const float* __restrict__ bout, const float* __restrict__ g,
    float* __restrict__ out)
{
  __shared__ __align__(16) ushort_t Qs[64 * 136];   // 17 KiB (padded rows)
  __shared__ float part_s[2][64], part_s2[2][64];
  __shared__ float st_mu[64], st_rs[64];

  const int tid = threadIdx.x;
  const int b = blockIdx.y;
  const int n0 = blockIdx.x * 64;
  const int w = tid >> 6, lane = tid & 63;
  const int half = lane >> 5, lm = lane & 31;
  const int ntile = w & 1, mgrp = w >> 1;

  // stage q' tile (padded pitch 136)
  {
    const int4* s2 = (const int4*)(qp + ((size_t)b * N_ + n0) * 128);
    for (int it = 0; it < 4; ++it) {
      int idx = tid + it * 256;
      int row = idx >> 4, c8 = idx & 15;
      *(int4*)(Qs + row * 136 + c8 * 8) = s2[idx];
    }
  }
  __syncthreads();

  f32x16 acc[4];
  for (int i = 0; i < 4; ++i)
    for (int r = 0; r < 16; ++r) acc[i][r] = 0.0f;

  {
    const ushort_t* wbase = weff + (size_t)b * 256 * 128
                          + (size_t)(mgrp * 4 * 32 + lm) * 128 + half * 8;
    for (int kc = 0; kc < 8; ++kc) {
      short8 bfrag = ld_frag16(Qs + (ntile * 32 + lm) * 136 + kc * 16 + half * 8);
      for (int i = 0; i < 4; ++i) {
        short8 af = ld_frag16(wbase + (size_t)i * 32 * 128 + kc * 16);
        acc[i] = __builtin_amdgcn_mfma_f32_32x32x16_bf16(af, bfrag, acc[i], 0, 0, 0);
      }
    }
  }

  float s = 0.0f, s2v = 0.0f;
  for (int i = 0; i < 4; ++i) {
    int mt = mgrp * 4 + i;
    for (int r = 0; r < 16; ++r) {
      int row = mt * 32 + (r & 3) + 8 * (r >> 2) + 4 * half;
      acc[i][r] += bout[row];
      float v = acc[i][r];
      s += v; s2v += v * v;
    }
  }
  s += __shfl_xor(s, 32);
  s2v += __shfl_xor(s2v, 32);
  if (half == 0) { part_s[mgrp][ntile * 32 + lm] = s; part_s2[mgrp][ntile * 32 + lm] = s2v; }
  __syncthreads();
  if (tid < 64) {
    float S = part_s[0][tid] + part_s[1][tid];
    float S2 = part_s2[0][tid] + part_s2[1][tid];
    float mu = S * (1.0f / 256.0f);
    float var = S2 * (1.0f / 256.0f) - mu * mu;
    st_mu[tid] = mu;
    st_rs[tid] = rsqrtf(var + EPS_);
  }
  __syncthreads();

  const int col = ntile * 32 + lm;
  const float mu = st_mu[col];
  const float rs = st_rs[col];
  float* ob = out + (size_t)b * C_ * N_ + n0 + col;
  for (int i = 0; i < 4; ++i) {
    int mt = mgrp * 4 + i;
    for (int r = 0; r < 16; ++r) {
      int row = mt * 32 + (r & 3) + 8 * (r >> 2) + 4 * half;
      ob[(size_t)row * N_] = (acc[i][r] - mu) * rs * g[row];
    }
  }
}

extern "C" void kernel_launch(void* const* d_in, const int* in_sizes, int n_in,
                              void* d_out, int out_size, void* d_ws, size_t ws_size,
                              hipStream_t stream) {
  (void)in_sizes; (void)n_in; (void)out_size; (void)ws_size;
  const float* x    = (const float*)d_in[0];
  const float* wqkv = (const float*)d_in[1];
  const float* wout = (const float*)d_in[2];
  const float* bout = (const float*)d_in[3];
  const float* g    = (const float*)d_in[4];
  float* out = (float*)d_out;

  char* ws = (char*)d_ws;
  ushort_t* qp   = (ushort_t*)(ws);                      // 16 MiB (b, n, 128) bf16
  float*    pctx = (float*)(ws + ((size_t)16 << 20));    // 16 MiB (b,h,64,32,32) fp32
  float*    psum = (float*)(ws + ((size_t)32 << 20));    // 512 KiB (b,h,64,32) fp32
  ushort_t* weff = (ushort_t*)(ws + ((size_t)33 << 20)); // 1 MiB (b,256,128) bf16
  ushort_t* wb   = (ushort_t*)(ws + ((size_t)34 << 20)); // 192 KiB (384,256) bf16

  k0_wconv<<<96, 256, 0, stream>>>(wqkv, wb);
  k1_qkv<<<dim3(64, 16), 256, 0, stream>>>(x, wb, qp, pctx, psum);
  k2b_weff<<<dim3(4, 16), 256, 0, stream>>>(pctx, psum, wout, weff);
  k3_out<<<dim3(64, 16), 256, 0, stream>>>(weff, qp, bout, g, out);
}

// Round 4
// 229.417 us; speedup vs baseline: 1.8900x; 1.1372x over previous
//
#include <hip/hip_runtime.h>

typedef short short8 __attribute__((ext_vector_type(8)));
typedef float f32x16 __attribute__((ext_vector_type(16)));
typedef unsigned short ushort_t;

#define B_    16
#define C_    256
#define N_    4096
#define H_    4
#define HID_  128
#define SCALE_ 0.17677669529663687f  /* 32^-0.5 */
#define EPS_  1e-5f

__device__ inline ushort_t f2bf(float f) {
  union { float f; unsigned u; } a; a.f = f;
  unsigned r = a.u + 0x7FFFu + ((a.u >> 16) & 1u);
  return (ushort_t)(r >> 16);
}

__device__ inline short8 ld_frag16(const ushort_t* p) {  // 16B-aligned
  return __builtin_bit_cast(short8, *(const int4*)p);
}
__device__ inline short8 ld_frag8(const ushort_t* p) {   // 8B-aligned (2x b64)
  int2 a = *(const int2*)p, b = *(const int2*)(p + 4);
  int4 t; t.x = a.x; t.y = a.y; t.z = b.x; t.w = b.y;
  return __builtin_bit_cast(short8, t);
}
__device__ inline short8 ld_frag4(const ushort_t* p) {   // 4B-aligned (4x b32)
  int4 t;
  t.x = *(const int*)(p);     t.y = *(const int*)(p + 2);
  t.z = *(const int*)(p + 4); t.w = *(const int*)(p + 6);
  return __builtin_bit_cast(short8, t);
}

// K0: build SWIZZLED bf16 W_qkv in MFMA A-fragment order:
//   wsw[((mt*16 + kc)*64 + lane)*8 + j] = W[mt*32 + (lane&31)][kc*16 + (lane>>5)*8 + j]
// so a wave's A-frag load is 64 lanes x 16 B contiguous (1 KB).
__global__ void k0_wswz(const float* __restrict__ w, ushort_t* __restrict__ wsw) {
  int gid = blockIdx.x * 256 + threadIdx.x;   // 0..12287 (12 tiles * 16 kc * 64 lanes)
  int lane = gid & 63, kc = (gid >> 6) & 15, mt = gid >> 10;
  int row = mt * 32 + (lane & 31);
  int col = kc * 16 + (lane >> 5) * 8;
  const float* src = w + (size_t)row * 256 + col;
  float4 a = *(const float4*)src, b = *(const float4*)(src + 4);
  union { ushort_t u[8]; int4 v; } o;
  o.u[0] = f2bf(a.x); o.u[1] = f2bf(a.y); o.u[2] = f2bf(a.z); o.u[3] = f2bf(a.w);
  o.u[4] = f2bf(b.x); o.u[5] = f2bf(b.y); o.u[6] = f2bf(b.z); o.u[7] = f2bf(b.w);
  *(int4*)(wsw + (size_t)gid * 8) = o.v;
}

// K1: qkv GEMM. X tile staged to LDS once (transposed, pitch 258 shorts);
// A-frags stream from the swizzled W (fully coalesced L2 hits).
// Fused epilogue: q-softmax -> qp; exp(k),v -> LDS -> partial context MFMA.
__global__ __launch_bounds__(256, 3) void k1_qkv(
    const float* __restrict__ x, const ushort_t* __restrict__ wsw,
    ushort_t* __restrict__ qp, float* __restrict__ pctx, float* __restrict__ psum)
{
  __shared__ __align__(16) union {
    struct { ushort_t Xs[64 * 258]; } s1;                                // 33 KiB
    struct { ushort_t Qt[64 * 132]; ushort_t kt[128 * 68]; ushort_t vt[128 * 68]; } s2; // 50.5 KiB
  } sm;

  const int tid = threadIdx.x;
  const int b = blockIdx.y;
  const int blk = blockIdx.x;
  const int n0 = blk * 64;
  const int w = tid >> 6, lane = tid & 63;
  const int half = lane >> 5, lm = lane & 31;
  const int ntile = w & 1, mgrp = w >> 1;

  f32x16 acc[6];
  for (int i = 0; i < 6; ++i)
    for (int r = 0; r < 16; ++r) acc[i][r] = 0.0f;

  // stage whole X tile transposed: Xs[nn][cc], pitch 258 shorts (129 dw)
  {
    const float* xb = x + (size_t)b * C_ * N_ + n0;
    for (int it = 0; it < 16; ++it) {
      int idx = it * 256 + tid;        // 0..4095
      int cc = idx >> 4;               // channel 0..255
      int n4 = idx & 15;               // group of 4 n
      float4 v = *(const float4*)(xb + (size_t)cc * N_ + n4 * 4);
      ushort_t* dst = sm.s1.Xs + cc;
      dst[(n4 * 4 + 0) * 258] = f2bf(v.x);
      dst[(n4 * 4 + 1) * 258] = f2bf(v.y);
      dst[(n4 * 4 + 2) * 258] = f2bf(v.z);
      dst[(n4 * 4 + 3) * 258] = f2bf(v.w);
    }
  }
  __syncthreads();

  // K-loop: B-frag from LDS, A-frag coalesced from swizzled global (L2)
  {
    const int nrow = ntile * 32 + lm;
    const ushort_t* wbase = wsw + ((size_t)(mgrp * 6) * 16 * 64 + lane) * 8;
    for (int kc = 0; kc < 16; ++kc) {
      short8 bfrag = ld_frag4(sm.s1.Xs + nrow * 258 + kc * 16 + half * 8);
      for (int i = 0; i < 6; ++i) {
        short8 af = ld_frag16(wbase + (size_t)((i * 16 + kc) * 64) * 8);
        acc[i] = __builtin_amdgcn_mfma_f32_32x32x16_bf16(af, bfrag, acc[i], 0, 0, 0);
      }
    }
  }
  __syncthreads();  // s1 dead; s2 live from here

  for (int i = 0; i < 6; ++i) {
    int mt = mgrp * 6 + i;
    if (mt < 4) {
      // q softmax over 32 rows (head dim) per column
      float m = -1e30f;
      for (int r = 0; r < 16; ++r) m = fmaxf(m, acc[i][r]);
      m = fmaxf(m, __shfl_xor(m, 32));
      float e[16]; float s = 0.0f;
      for (int r = 0; r < 16; ++r) { e[r] = __expf(acc[i][r] - m); s += e[r]; }
      s += __shfl_xor(s, 32);
      float sc = SCALE_ / s;
      for (int r = 0; r < 16; ++r) {
        int row = (r & 3) + 8 * (r >> 2) + 4 * half;
        sm.s2.Qt[(ntile * 32 + lm) * 132 + mt * 32 + row] = f2bf(e[r] * sc);
      }
    } else if (mt < 8) {
      int kr = (mt - 4) * 32;
      for (int r = 0; r < 16; ++r) {
        int row = (r & 3) + 8 * (r >> 2) + 4 * half;
        sm.s2.kt[(kr + row) * 68 + ntile * 32 + lm] = f2bf(__expf(acc[i][r]));
      }
    } else {
      int vr = (mt - 8) * 32;
      for (int r = 0; r < 16; ++r) {
        int row = (r & 3) + 8 * (r >> 2) + 4 * half;
        sm.s2.vt[(vr + row) * 68 + ntile * 32 + lm] = f2bf(acc[i][r]);
      }
    }
  }
  __syncthreads();

  // per-head partial context via MFMA; wave w handles head w
  {
    const int h = w;
    f32x16 cacc, eacc;
    for (int r = 0; r < 16; ++r) { cacc[r] = 0.0f; eacc[r] = 0.0f; }
    short8 ones;
    for (int j = 0; j < 8; ++j) ones[j] = (short)0x3F80;  // bf16 1.0
    for (int nb = 0; nb < 4; ++nb) {
      short8 af = ld_frag8(sm.s2.kt + (h * 32 + lm) * 68 + nb * 16 + half * 8);
      short8 bf = ld_frag8(sm.s2.vt + (h * 32 + lm) * 68 + nb * 16 + half * 8);
      cacc = __builtin_amdgcn_mfma_f32_32x32x16_bf16(af, bf, cacc, 0, 0, 0);
      eacc = __builtin_amdgcn_mfma_f32_32x32x16_bf16(af, ones, eacc, 0, 0, 0);
    }
    float* pc = pctx + ((size_t)(b * H_ + h) * 64 + blk) * 1024;
    for (int r = 0; r < 16; ++r) {
      int row = (r & 3) + 8 * (r >> 2) + 4 * half;
      pc[row * 32 + lm] = cacc[r];
    }
    if (lm == 0) {
      float* ps = psum + ((size_t)(b * H_ + h) * 64 + blk) * 32;
      for (int r = 0; r < 16; ++r) {
        int row = (r & 3) + 8 * (r >> 2) + 4 * half;
        ps[row] = eacc[r];
      }
    }
  }
  __syncthreads();

  // coalesced copy Qt -> qp[b][n0..n0+63][128]
  {
    int4* dst = (int4*)(qp + ((size_t)b * N_ + n0) * 128);
    for (int it = 0; it < 4; ++it) {
      int idx = tid + it * 256;              // 0..1023
      int row = idx >> 4, c8 = idx & 15;
      const ushort_t* src = sm.s2.Qt + row * 132 + c8 * 8;
      int2 u0 = *(const int2*)src, u1 = *(const int2*)(src + 4);
      int4 o; o.x = u0.x; o.y = u0.y; o.z = u1.x; o.w = u1.y;
      dst[idx] = o;
    }
  }
}

// K2b: reduce 64 partials per (b,h), normalize, pre-contract with w_out,
// and write weff in SWIZZLED k3-A-fragment order:
//   weff[b*32768 + ((mt*8+kc)*64 + half*32 + lm)*8 + j] = Weff[oc=mt*32+lm][kc*16+half*8+j]
__global__ __launch_bounds__(256) void k2b_weff(
    const float* __restrict__ pctx, const float* __restrict__ psum,
    const float* __restrict__ wout, ushort_t* __restrict__ weff)
{
  __shared__ float ctxs[32][32];
  __shared__ float inv[32];
  const int tid = threadIdx.x;
  const int h = blockIdx.x, b = blockIdx.y;
  if (tid < 32) {
    float s = 0.0f;
    const float* ps = psum + (size_t)(b * H_ + h) * 64 * 32 + tid;
    for (int blkk = 0; blkk < 64; ++blkk) s += ps[blkk * 32];
    inv[tid] = 1.0f / (s * 4096.0f);
  }
  __syncthreads();
  for (int it = 0; it < 4; ++it) {
    int de = tid + it * 256;
    float s = 0.0f;
    const float* pc = pctx + (size_t)(b * H_ + h) * 64 * 1024 + de;
    for (int blkk = 0; blkk < 64; ++blkk) s += pc[blkk * 1024];
    ctxs[de >> 5][de & 31] = s * inv[de >> 5];
  }
  __syncthreads();
  const int oc = tid;
  const int mt = oc >> 5, lmm = oc & 31;
  const float* wrow = wout + (size_t)oc * HID_ + h * 32;
  float wr[32];
  for (int e = 0; e < 32; ++e) wr[e] = wrow[e];
  float vals[32];
  for (int d = 0; d < 32; ++d) {
    float s = 0.0f;
    for (int e = 0; e < 32; ++e) s += wr[e] * ctxs[d][e];
    vals[d] = s;
  }
  // this head's dh range is [h*32, h*32+32) -> kc = h*2 + {0,1}, half = {0,1}
  ushort_t* wb_b = weff + (size_t)b * 32768;
  for (int kci = 0; kci < 2; ++kci) {
    int kc = h * 2 + kci;
    for (int hf = 0; hf < 2; ++hf) {
      int d0 = kci * 16 + hf * 8;
      union { ushort_t u[8]; int4 v; } o;
      for (int j = 0; j < 8; ++j) o.u[j] = f2bf(vals[d0 + j]);
      *(int4*)(wb_b + (size_t)((mt * 8 + kc) * 64 + hf * 32 + lmm) * 8) = o.v;
    }
  }
}

// K3: out = W_eff_b @ q'^T + b_out, channel LayerNorm per column, * g, fp32 store.
// A-frags stream coalesced from swizzled weff; q' in LDS (pitch 132, b64 frags).
__global__ __launch_bounds__(256, 4) void k3_out(
    const ushort_t* __restrict__ weff, const ushort_t* __restrict__ qp,
    const float* __restrict__ bout, const float* __restrict__ g,
    float* __restrict__ out)
{
  __shared__ __align__(16) ushort_t Qs[64 * 132];   // 16.5 KiB
  __shared__ float part_s[2][64], part_s2[2][64];
  __shared__ float st_mu[64], st_rs[64];

  const int tid = threadIdx.x;
  const int b = blockIdx.y;
  const int n0 = blockIdx.x * 64;
  const int w = tid >> 6, lane = tid & 63;
  const int half = lane >> 5, lm = lane & 31;
  const int ntile = w & 1, mgrp = w >> 1;

  // stage q' tile (pitch 132 shorts; odd-row base is 8B-aligned -> int2 pairs)
  {
    const int4* s2 = (const int4*)(qp + ((size_t)b * N_ + n0) * 128);
    for (int it = 0; it < 4; ++it) {
      int idx = tid + it * 256;
      int row = idx >> 4, c8 = idx & 15;
      int4 v = s2[idx];
      ushort_t* dst = Qs + row * 132 + c8 * 8;
      *(int2*)dst = make_int2(v.x, v.y);
      *(int2*)(dst + 4) = make_int2(v.z, v.w);
    }
  }
  __syncthreads();

  f32x16 acc[4];
  for (int i = 0; i < 4; ++i)
    for (int r = 0; r < 16; ++r) acc[i][r] = 0.0f;

  {
    const ushort_t* wbase = weff + (size_t)b * 32768 + ((size_t)(mgrp * 4) * 8 * 64 + lane) * 8;
    for (int kc = 0; kc < 8; ++kc) {
      short8 bfrag = ld_frag8(Qs + (ntile * 32 + lm) * 132 + kc * 16 + half * 8);
      for (int i = 0; i < 4; ++i) {
        short8 af = ld_frag16(wbase + (size_t)((i * 8 + kc) * 64) * 8);
        acc[i] = __builtin_amdgcn_mfma_f32_32x32x16_bf16(af, bfrag, acc[i], 0, 0, 0);
      }
    }
  }

  float s = 0.0f, s2v = 0.0f;
  for (int i = 0; i < 4; ++i) {
    int mt = mgrp * 4 + i;
    for (int r = 0; r < 16; ++r) {
      int row = mt * 32 + (r & 3) + 8 * (r >> 2) + 4 * half;
      acc[i][r] += bout[row];
      float v = acc[i][r];
      s += v; s2v += v * v;
    }
  }
  s += __shfl_xor(s, 32);
  s2v += __shfl_xor(s2v, 32);
  if (half == 0) { part_s[mgrp][ntile * 32 + lm] = s; part_s2[mgrp][ntile * 32 + lm] = s2v; }
  __syncthreads();
  if (tid < 64) {
    float S = part_s[0][tid] + part_s[1][tid];
    float S2 = part_s2[0][tid] + part_s2[1][tid];
    float mu = S * (1.0f / 256.0f);
    float var = S2 * (1.0f / 256.0f) - mu * mu;
    st_mu[tid] = mu;
    st_rs[tid] = rsqrtf(var + EPS_);
  }
  __syncthreads();

  const int col = ntile * 32 + lm;
  const float mu = st_mu[col];
  const float rs = st_rs[col];
  float* ob = out + (size_t)b * C_ * N_ + n0 + col;
  for (int i = 0; i < 4; ++i) {
    int mt = mgrp * 4 + i;
    for (int r = 0; r < 16; ++r) {
      int row = mt * 32 + (r & 3) + 8 * (r >> 2) + 4 * half;
      ob[(size_t)row * N_] = (acc[i][r] - mu) * rs * g[row];
    }
  }
}

extern "C" void kernel_launch(void* const* d_in, const int* in_sizes, int n_in,
                              void* d_out, int out_size, void* d_ws, size_t ws_size,
                              hipStream_t stream) {
  (void)in_sizes; (void)n_in; (void)out_size; (void)ws_size;
  const float* x    = (const float*)d_in[0];
  const float* wqkv = (const float*)d_in[1];
  const float* wout = (const float*)d_in[2];
  const float* bout = (const float*)d_in[3];
  const float* g    = (const float*)d_in[4];
  float* out = (float*)d_out;

  char* ws = (char*)d_ws;
  ushort_t* qp   = (ushort_t*)(ws);                      // 16 MiB (b, n, 128) bf16
  float*    pctx = (float*)(ws + ((size_t)16 << 20));    // 16 MiB (b,h,64,32,32) fp32
  float*    psum = (float*)(ws + ((size_t)32 << 20));    // 512 KiB (b,h,64,32) fp32
  ushort_t* weff = (ushort_t*)(ws + ((size_t)33 << 20)); // 1 MiB (b,256,128) bf16 swizzled
  ushort_t* wsw  = (ushort_t*)(ws + ((size_t)34 << 20)); // 192 KiB swizzled W_qkv bf16

  k0_wswz<<<48, 256, 0, stream>>>(wqkv, wsw);
  k1_qkv<<<dim3(64, 16), 256, 0, stream>>>(x, wsw, qp, pctx, psum);
  k2b_weff<<<dim3(4, 16), 256, 0, stream>>>(pctx, psum, wout, weff);
  k3_out<<<dim3(64, 16), 256, 0, stream>>>(weff, qp, bout, g, out);
}

// Round 7
// 168.575 us; speedup vs baseline: 2.5722x; 1.3609x over previous
//
#include <hip/hip_runtime.h>

typedef short short8 __attribute__((ext_vector_type(8)));
typedef float f32x16 __attribute__((ext_vector_type(16)));
typedef unsigned short ushort_t;

#define B_    16
#define C_    256
#define N_    4096
#define H_    4
#define HID_  128
#define SCALE_ 0.17677669529663687f  /* 32^-0.5 */
#define EPS_  1e-5f

__device__ inline ushort_t f2bf(float f) {
  union { float f; unsigned u; } a; a.f = f;
  unsigned r = a.u + 0x7FFFu + ((a.u >> 16) & 1u);
  return (ushort_t)(r >> 16);
}

__device__ inline short8 ld_frag16(const ushort_t* p) {  // 16B-aligned
  return __builtin_bit_cast(short8, *(const int4*)p);
}
__device__ inline short8 ld_frag8(const ushort_t* p) {   // 8B-aligned
  int2 a = *(const int2*)p, b = *(const int2*)(p + 4);
  int4 t; t.x = a.x; t.y = a.y; t.z = b.x; t.w = b.y;
  return __builtin_bit_cast(short8, t);
}

// K0: swizzled bf16 W_qkv in MFMA A-fragment order (R4-validated):
//   wsw[((mt*16 + kc)*64 + lane)*8 + j] = W[mt*32 + (lane&31)][kc*16 + (lane>>5)*8 + j]
__global__ void k0_wswz(const float* __restrict__ w, ushort_t* __restrict__ wsw) {
  int gid = blockIdx.x * 256 + threadIdx.x;   // 12288
  int ln = gid & 63, kc = (gid >> 6) & 15, mt = gid >> 10;
  int row = mt * 32 + (ln & 31);
  int col = kc * 16 + (ln >> 5) * 8;
  const float* src = w + (size_t)row * 256 + col;
  float4 a = *(const float4*)src, b = *(const float4*)(src + 4);
  union { ushort_t u[8]; int4 v; } o;
  o.u[0] = f2bf(a.x); o.u[1] = f2bf(a.y); o.u[2] = f2bf(a.z); o.u[3] = f2bf(a.w);
  o.u[4] = f2bf(b.x); o.u[5] = f2bf(b.y); o.u[6] = f2bf(b.z); o.u[7] = f2bf(b.w);
  *(int4*)(wsw + (size_t)gid * 8) = o.v;
}

// K1: 512 threads, 8 waves. Wave w: hw=w>>1 (head), ntile=w&1 (32-col half).
// Wave owns 3 acc tiles: mt = hw (q), 4+hw (k), 8+hw (v) over its 32 cols.
// Epilogue: q-softmax -> DIRECT global stores in k3 B-frag order;
// exp(k),v -> LDS kt/vt; psum via shfl butterfly; ctx MFMA by ntile==0 waves.
__global__ __launch_bounds__(512, 4) void k1_qkv(
    const float* __restrict__ x, const ushort_t* __restrict__ wsw,
    ushort_t* __restrict__ qp, float* __restrict__ pctx, float* __restrict__ psum)
{
  __shared__ __align__(16) union {
    ushort_t Xs[64 * 264];                                   // 33 KiB
    struct { ushort_t kt[128 * 68]; ushort_t vt[128 * 68]; } s2;  // 34 KiB
  } sm;

  const int tid = threadIdx.x;
  const int b = blockIdx.y;
  const int blk = blockIdx.x;
  const int n0 = blk * 64;
  const int w = tid >> 6, lane = tid & 63;
  const int half = lane >> 5, lm = lane & 31;
  const int hw = w >> 1, ntile = w & 1;
  const int gnt = blk * 2 + ntile;

  // ---- stage X tile transposed: Xs[n][c], pitch 264 shorts ----
  {
    const float* xb = x + (size_t)b * C_ * N_ + n0;
    for (int it = 0; it < 8; ++it) {
      int idx = it * 512 + tid;        // 0..4095
      int cc = idx >> 4, n4 = idx & 15;
      float4 v = *(const float4*)(xb + (size_t)cc * N_ + n4 * 4);
      ushort_t* dst = sm.Xs + cc;
      dst[(n4 * 4 + 0) * 264] = f2bf(v.x);
      dst[(n4 * 4 + 1) * 264] = f2bf(v.y);
      dst[(n4 * 4 + 2) * 264] = f2bf(v.z);
      dst[(n4 * 4 + 3) * 264] = f2bf(v.w);
    }
  }
  __syncthreads();

  // ---- GEMM: 3 acc tiles (q,k,v rows of this head), 16 K-chunks ----
  f32x16 acc0, acc1, acc2;
  for (int r = 0; r < 16; ++r) { acc0[r] = 0.0f; acc1[r] = 0.0f; acc2[r] = 0.0f; }
  {
    const ushort_t* xrow = sm.Xs + (ntile * 32 + lm) * 264 + half * 8;
    for (int kc = 0; kc < 16; ++kc) {
      short8 bfrag = ld_frag16(xrow + kc * 16);
      short8 a0 = ld_frag16(wsw + (size_t)(((hw) * 16 + kc) * 64 + lane) * 8);
      short8 a1 = ld_frag16(wsw + (size_t)(((4 + hw) * 16 + kc) * 64 + lane) * 8);
      short8 a2 = ld_frag16(wsw + (size_t)(((8 + hw) * 16 + kc) * 64 + lane) * 8);
      acc0 = __builtin_amdgcn_mfma_f32_32x32x16_bf16(a0, bfrag, acc0, 0, 0, 0);
      acc1 = __builtin_amdgcn_mfma_f32_32x32x16_bf16(a1, bfrag, acc1, 0, 0, 0);
      acc2 = __builtin_amdgcn_mfma_f32_32x32x16_bf16(a2, bfrag, acc2, 0, 0, 0);
    }
  }

  // ---- q: softmax over d, direct global store in k3 B-frag order ----
  {
    float m = -1e30f;
    for (int r = 0; r < 16; ++r) m = fmaxf(m, acc0[r]);
    m = fmaxf(m, __shfl_xor(m, 32));
    float s = 0.0f;
    for (int r = 0; r < 16; ++r) s += __expf(acc0[r] - m);
    s += __shfl_xor(s, 32);
    float sc = SCALE_ / s;
    ushort_t* qpb = qp + (size_t)b * N_ * 128;
    for (int q = 0; q < 4; ++q) {
      int kc = hw * 2 + (q >> 1);
      int fl = (q & 1) * 32 + lm;
      float v0 = __expf(acc0[q * 4 + 0] - m) * sc;
      float v1 = __expf(acc0[q * 4 + 1] - m) * sc;
      float v2 = __expf(acc0[q * 4 + 2] - m) * sc;
      float v3 = __expf(acc0[q * 4 + 3] - m) * sc;
      int2 o;
      o.x = (int)f2bf(v0) | ((int)f2bf(v1) << 16);
      o.y = (int)f2bf(v2) | ((int)f2bf(v3) << 16);
      *(int2*)(qpb + (size_t)((gnt * 8 + kc) * 64 + fl) * 8 + 4 * half) = o;
    }
  }

  // ---- k: exp in regs ----
  float ev[16];
  for (int r = 0; r < 16; ++r) ev[r] = __expf(acc1[r]);

  __syncthreads();   // all waves done reading Xs; s2 live

  // kt/vt writes (d-major, pitch 68)
  for (int r = 0; r < 16; ++r) {
    int row = (r & 3) + 8 * (r >> 2) + 4 * half;
    sm.s2.kt[(hw * 32 + row) * 68 + ntile * 32 + lm] = f2bf(ev[r]);
    sm.s2.vt[(hw * 32 + row) * 68 + ntile * 32 + lm] = f2bf(acc2[r]);
  }

  // psum: butterfly-sum ev over the 32 cols (lanes) of this wave's half
  for (int mask = 1; mask <= 16; mask <<= 1)
    for (int r = 0; r < 16; ++r) ev[r] += __shfl_xor(ev[r], mask);
  if (lm == 0) {
    float* ps = psum + ((size_t)(b * 4 + hw) * 128 + gnt) * 32;
    for (int r = 0; r < 16; ++r) {
      int row = (r & 3) + 8 * (r >> 2) + 4 * half;
      ps[row] = ev[r];
    }
  }
  __syncthreads();

  // ---- ctx partial (ntile==0 waves, full 64 cols): ctx[d][e] = sum expk*v ----
  if (ntile == 0) {
    f32x16 cacc;
    for (int r = 0; r < 16; ++r) cacc[r] = 0.0f;
    const ushort_t* ka = sm.s2.kt + (hw * 32 + lm) * 68 + half * 8;
    const ushort_t* va = sm.s2.vt + (hw * 32 + lm) * 68 + half * 8;
    for (int s = 0; s < 4; ++s) {
      short8 af = ld_frag8(ka + s * 16);
      short8 bf = ld_frag8(va + s * 16);
      cacc = __builtin_amdgcn_mfma_f32_32x32x16_bf16(af, bf, cacc, 0, 0, 0);
    }
    float* pc = pctx + ((size_t)(b * 4 + hw) * 64 + blk) * 1024;
    for (int r = 0; r < 16; ++r) {
      int row = (r & 3) + 8 * (r >> 2) + 4 * half;
      pc[row * 32 + lm] = cacc[r];
    }
  }
}

// K2b: reduce partials, normalize (denom & 1/4096), pre-contract with w_out,
// write weff in k3 A-frag swizzled order.
__global__ __launch_bounds__(256) void k2b_weff(
    const float* __restrict__ pctx, const float* __restrict__ psum,
    const float* __restrict__ wout, ushort_t* __restrict__ weff)
{
  __shared__ float ctxs[32][32];
  __shared__ float inv[32];
  const int tid = threadIdx.x;
  const int ph = blockIdx.x, pb = blockIdx.y;
  const size_t bh = (size_t)(pb * 4 + ph);
  if (tid < 32) {
    float s = 0.0f;
    const float* ps = psum + bh * 128 * 32 + tid;
    #pragma unroll 8
    for (int c = 0; c < 128; ++c) s += ps[c * 32];
    inv[tid] = 1.0f / (s * 4096.0f);
  }
  __syncthreads();
  {
    float4 s4 = make_float4(0.f, 0.f, 0.f, 0.f);
    const float* pc = pctx + bh * 64 * 1024 + tid * 4;
    #pragma unroll 8
    for (int c = 0; c < 64; ++c) {
      float4 v = *(const float4*)(pc + c * 1024);
      s4.x += v.x; s4.y += v.y; s4.z += v.z; s4.w += v.w;
    }
    int d = tid >> 3;
    float iv = inv[d];
    float* crow = &ctxs[0][0] + tid * 4;
    crow[0] = s4.x * iv; crow[1] = s4.y * iv; crow[2] = s4.z * iv; crow[3] = s4.w * iv;
  }
  __syncthreads();
  {
    const int oc = tid;
    const int mt = oc >> 5, lmm = oc & 31;
    const float* wrow = wout + (size_t)oc * HID_ + ph * 32;
    float wr[32];
    for (int e = 0; e < 32; ++e) wr[e] = wrow[e];
    float vals[32];
    for (int d = 0; d < 32; ++d) {
      float s = 0.0f;
      for (int e = 0; e < 32; ++e) s += wr[e] * ctxs[d][e];
      vals[d] = s;
    }
    ushort_t* wb_b = weff + (size_t)pb * 32768;
    for (int kci = 0; kci < 2; ++kci) {
      int kc = ph * 2 + kci;
      for (int hf = 0; hf < 2; ++hf) {
        int d0 = kci * 16 + hf * 8;
        union { ushort_t u[8]; int4 v; } o;
        for (int j = 0; j < 8; ++j) o.u[j] = f2bf(vals[d0 + j]);
        *(int4*)(wb_b + (size_t)((mt * 8 + kc) * 64 + hf * 32 + lmm) * 8) = o.v;
      }
    }
  }
}

// K3: out = W_eff_b @ q'^T + b_out, LayerNorm per column, fp32 store.
// A-frags from swizzled weff, B-frags from swizzled qp — no LDS staging.
__global__ __launch_bounds__(256, 4) void k3_out(
    const ushort_t* __restrict__ weff, const ushort_t* __restrict__ qp,
    const float* __restrict__ bout, const float* __restrict__ g,
    float* __restrict__ out)
{
  __shared__ float part_s[2][64], part_s2[2][64];
  __shared__ float st_mu[64], st_rs[64];

  const int tid = threadIdx.x;
  const int b = blockIdx.y;
  const int blk = blockIdx.x;
  const int n0 = blk * 64;
  const int w = tid >> 6, lane = tid & 63;
  const int half = lane >> 5, lm = lane & 31;
  const int ntile = w & 1, mgrp = w >> 1;
  const int gnt = blk * 2 + ntile;

  f32x16 acc[4];
  for (int i = 0; i < 4; ++i)
    for (int r = 0; r < 16; ++r) acc[i][r] = 0.0f;

  {
    const ushort_t* qb = qp + (size_t)b * N_ * 128 + (size_t)gnt * 8 * 64 * 8;
    const ushort_t* wbase = weff + (size_t)b * 32768 + ((size_t)(mgrp * 4) * 8 * 64 + lane) * 8;
    for (int kc = 0; kc < 8; ++kc) {
      short8 bfrag = ld_frag16(qb + (size_t)(kc * 64 + lane) * 8);
      for (int i = 0; i < 4; ++i) {
        short8 af = ld_frag16(wbase + (size_t)((i * 8 + kc) * 64) * 8);
        acc[i] = __builtin_amdgcn_mfma_f32_32x32x16_bf16(af, bfrag, acc[i], 0, 0, 0);
      }
    }
  }

  float s = 0.0f, s2v = 0.0f;
  for (int i = 0; i < 4; ++i) {
    int mt = mgrp * 4 + i;
    for (int r = 0; r < 16; ++r) {
      int row = mt * 32 + (r & 3) + 8 * (r >> 2) + 4 * half;
      acc[i][r] += bout[row];
      float v = acc[i][r];
      s += v; s2v += v * v;
    }
  }
  s += __shfl_xor(s, 32);
  s2v += __shfl_xor(s2v, 32);
  if (half == 0) { part_s[mgrp][ntile * 32 + lm] = s; part_s2[mgrp][ntile * 32 + lm] = s2v; }
  __syncthreads();
  if (tid < 64) {
    float S = part_s[0][tid] + part_s[1][tid];
    float S2 = part_s2[0][tid] + part_s2[1][tid];
    float mu = S * (1.0f / 256.0f);
    float var = S2 * (1.0f / 256.0f) - mu * mu;
    st_mu[tid] = mu;
    st_rs[tid] = rsqrtf(var + EPS_);
  }
  __syncthreads();

  const int col = ntile * 32 + lm;
  const float mu = st_mu[col];
  const float rs = st_rs[col];
  float* ob = out + (size_t)b * C_ * N_ + n0 + col;
  for (int i = 0; i < 4; ++i) {
    int mt = mgrp * 4 + i;
    for (int r = 0; r < 16; ++r) {
      int row = mt * 32 + (r & 3) + 8 * (r >> 2) + 4 * half;
      ob[(size_t)row * N_] = (acc[i][r] - mu) * rs * g[row];
    }
  }
}

extern "C" void kernel_launch(void* const* d_in, const int* in_sizes, int n_in,
                              void* d_out, int out_size, void* d_ws, size_t ws_size,
                              hipStream_t stream) {
  (void)in_sizes; (void)n_in; (void)out_size; (void)ws_size;
  const float* x    = (const float*)d_in[0];
  const float* wqkv = (const float*)d_in[1];
  const float* wout = (const float*)d_in[2];
  const float* bout = (const float*)d_in[3];
  const float* g    = (const float*)d_in[4];
  float* out = (float*)d_out;

  char* ws = (char*)d_ws;
  ushort_t* qp   = (ushort_t*)(ws);                      // 16 MiB swizzled q' bf16
  float*    pctx = (float*)(ws + ((size_t)16 << 20));    // 16 MiB (b,h,64,32,32) fp32
  float*    psum = (float*)(ws + ((size_t)32 << 20));    // 1 MiB  (b,h,128,32) fp32
  ushort_t* weff = (ushort_t*)(ws + ((size_t)33 << 20)); // 1 MiB swizzled
  ushort_t* wsw  = (ushort_t*)(ws + ((size_t)34 << 20)); // 192 KiB swizzled W_qkv

  k0_wswz<<<48, 256, 0, stream>>>(wqkv, wsw);
  k1_qkv<<<dim3(64, 16), 512, 0, stream>>>(x, wsw, qp, pctx, psum);
  k2b_weff<<<dim3(4, 16), 256, 0, stream>>>(pctx, psum, wout, weff);
  k3_out<<<dim3(64, 16), 256, 0, stream>>>(weff, qp, bout, g, out);
}